// Round 10
// baseline (189.065 us; speedup 1.0000x reference)
//
#include <hip/hip_runtime.h>

// SpatialTransformer: 3D trilinear warp, zeros padding.
// src [B,C,D,H,W] f32 = [2,2,128,160,128]; flow [B,3,D,H,W]; out [B,C,D,H,W].
//
// R18: CHANNEL-SPLIT TWO-PHASE on the R16 structure (best: 56.4us).
// R17 falsified blocks/CU as a lever (60.3us: +occupancy, -HBM; in-phase
// blocks add traffic not overlap; staged/output 3.83->5.47 hurt).
// R16's residual: {issue -> vmcnt(0) drain -> compute} = memory idle
// during compute, VALU idle during drain. The tile's natural seam: the
// two CHANNEL planes are compute-independent with a shared weight chain.
//  - Issue plane0 DMA + flow, sched_barrier, issue plane1 DMA.
//  - s_waitcnt vmcnt(4) (= plane1's per-wave instr count; staging padded
//    to 4 UNCONDITIONAL DMA instrs/wave/plane -> uniform count) + raw
//    s_barrier -> compute ch0; per-pair indices/weights kept in named
//    structs (rule-#20 static access).
//  - s_waitcnt vmcnt(0) (plane1 landed under ch0 compute) + s_barrier ->
//    ch1 = 8 LDS reads + blends, weights reused. T3/T4 counted-vmcnt
//    pattern; sched_barrier(0) fences pin issue order + waits (rule #18).
//  - LDS: 2 x 8192-float padded planes = 64 KB -> 2 blocks/CU (128 KB).
//    Padding rows (196..204) are clamped-garbage, never read.
//  - Geometry = R16: z8 y8 x32, 512 thr, 4 x-pairs/thread, grid 2560.
// Spill tripwire: VGPR cap 128 @ (512,4); if exceeded -> WRITE_SIZE
// balloons (R11 signature) -> shed state next round.
// Falsification pre-commit: clean >=55us -> declare serial-chain wall.

#define B_ 2
#define C_ 2
#define D_ 128
#define H_ 160
#define W_ 128
constexpr int S_ = D_ * H_ * W_;

#define ZT 8
#define YT 8
#define XT 32
#define RZ 3
#define RY 3
#define RX 4
#define CZ (ZT + 2 * RZ)   // 14
#define CY (YT + 2 * RY)   // 14
#define CX (XT + 2 * RX)   // 40
#define NTHREADS 512
#define PLANE_PAD 8192     // padded plane floats (real: 14*14*40 = 7840)

typedef const __attribute__((address_space(1))) unsigned int ga_u32;
typedef __attribute__((address_space(3))) unsigned int lds_u32;

__device__ __forceinline__ void gload16(const float* g, float* l) {
    // 16B global->LDS DMA; zero VGPR dest, vmcnt-tracked.
    __builtin_amdgcn_global_load_lds((ga_u32*)g, (lds_u32*)l, 16, 0, 0);
}

// Per-pair cross-phase state. Members accessed statically only (rule #20).
struct PState {
    int o00, o01, o10, o11;              // LDS plane offsets (fast) or global idx
    float w00, w01, w10, w11, wx0, wx1;  // combined z*y weights + x weights
    bool hi0, lo1, fast;
};

__device__ __forceinline__ PState mk_state(
    int x, int y, int z, float fz, float fy, float fx,
    int zb, int yb, int xb,
    int zlo, int zhi, int ylo, int yhi, int xlo, int xhi)
{
    const float iz = (float)z + fz;
    const float iy = (float)y + fy;
    const float ix = (float)x + fx;

    const float zf = floorf(iz), yf = floorf(iy), xf = floorf(ix);
    const float tz = iz - zf, ty = iy - yf, tx = ix - xf;
    const int z0 = (int)zf, y0 = (int)yf, x0 = (int)xf;

    const int zc0 = min(max(z0, 0), D_ - 1), zc1 = min(max(z0 + 1, 0), D_ - 1);
    const int yc0 = min(max(y0, 0), H_ - 1), yc1 = min(max(y0 + 1, 0), H_ - 1);
    const int xp  = min(max(x0, 0), W_ - 2);

    const float wz0 = ((unsigned)z0       < (unsigned)D_) ? (1.f - tz) : 0.f;
    const float wz1 = ((unsigned)(z0 + 1) < (unsigned)D_) ? tz         : 0.f;
    const float wy0 = ((unsigned)y0       < (unsigned)H_) ? (1.f - ty) : 0.f;
    const float wy1 = ((unsigned)(y0 + 1) < (unsigned)H_) ? ty         : 0.f;

    PState st;
    st.wx0 = ((unsigned)x0       < (unsigned)W_) ? (1.f - tx) : 0.f;
    st.wx1 = ((unsigned)(x0 + 1) < (unsigned)W_) ? tx         : 0.f;
    st.hi0 = x0 > xp;   // x0 == W-1
    st.lo1 = x0 < xp;   // x0 == -1
    st.w00 = wz0 * wy0; st.w01 = wz0 * wy1;
    st.w10 = wz1 * wy0; st.w11 = wz1 * wy1;
    st.fast = (zc0 >= zlo) & (zc1 < zhi) &
              (yc0 >= ylo) & (yc1 < yhi) &
              (xp >= xlo) & (xp + 1 < xhi);
    if (st.fast) {
        const int izl0 = zc0 - (zb - RZ), izl1 = zc1 - (zb - RZ);
        const int iyl0 = yc0 - (yb - RY), iyl1 = yc1 - (yb - RY);
        const int ixl  = xp - (xb - RX);
        st.o00 = (izl0 * CY + iyl0) * CX + ixl;
        st.o01 = (izl0 * CY + iyl1) * CX + ixl;
        st.o10 = (izl1 * CY + iyl0) * CX + ixl;
        st.o11 = (izl1 * CY + iyl1) * CX + ixl;
    } else {
        st.o00 = (zc0 * H_ + yc0) * W_ + xp;
        st.o01 = (zc0 * H_ + yc1) * W_ + xp;
        st.o10 = (zc1 * H_ + yc0) * W_ + xp;
        st.o11 = (zc1 * H_ + yc1) * W_ + xp;
    }
    return st;
}

// Evaluate one channel from saved state. ldsp = this channel's LDS plane,
// gp = this channel's global base (fallback).
__device__ __forceinline__ float eval_ch(const PState& st,
                                         const float* __restrict__ ldsp,
                                         const float* __restrict__ gp)
{
    float a00, b00, a01, b01, a10, b10, a11, b11;
    if (st.fast) {
        a00 = ldsp[st.o00]; b00 = ldsp[st.o00 + 1];
        a01 = ldsp[st.o01]; b01 = ldsp[st.o01 + 1];
        a10 = ldsp[st.o10]; b10 = ldsp[st.o10 + 1];
        a11 = ldsp[st.o11]; b11 = ldsp[st.o11 + 1];
    } else {
        a00 = gp[st.o00]; b00 = gp[st.o00 + 1];
        a01 = gp[st.o01]; b01 = gp[st.o01 + 1];
        a10 = gp[st.o10]; b10 = gp[st.o10 + 1];
        a11 = gp[st.o11]; b11 = gp[st.o11 + 1];
    }
    const float q00 = st.wx0 * (st.hi0 ? b00 : a00) + st.wx1 * (st.lo1 ? a00 : b00);
    const float q01 = st.wx0 * (st.hi0 ? b01 : a01) + st.wx1 * (st.lo1 ? a01 : b01);
    const float q10 = st.wx0 * (st.hi0 ? b10 : a10) + st.wx1 * (st.lo1 ? a10 : b10);
    const float q11 = st.wx0 * (st.hi0 ? b11 : a11) + st.wx1 * (st.lo1 ? a11 : b11);
    return st.w00 * q00 + st.w01 * q01 + st.w10 * q10 + st.w11 * q11;
}

__global__ __launch_bounds__(NTHREADS, 4) void warp3d_tile(
    const float* __restrict__ src,
    const float* __restrict__ flow,
    float* __restrict__ out)
{
    __shared__ float tile[2 * PLANE_PAD];   // 64 KB

    const int tid = threadIdx.x;
    const int xb = blockIdx.x * XT;
    const int yb = blockIdx.y * YT;
    const int bz = blockIdx.z;
    const int zb = (bz & 15) * ZT;         // 16 z-tiles
    const int b  = bz >> 4;                // batch

    const float* fb = flow + (long long)b * 3 * S_;
    const float* s0 = src + (long long)b * C_ * S_;   // ch0; ch1 = s0 + S_
    float* o0       = out + (long long)b * C_ * S_;

    // ---- staging plane0: 4 UNCONDITIONAL DMA instrs per wave (padded) ----
#pragma unroll
    for (int j = 0; j < 4; ++j) {
        const int lin = j * NTHREADS + tid;            // 0..2047
        const int row = lin / 10;
        const int cq  = lin - row * 10;
        const int rz = row / CY, ry = row - rz * CY;
        const int gz = min(max(zb - RZ + rz, 0), D_ - 1);
        const int gy = min(max(yb - RY + ry, 0), H_ - 1);
        const int gx = min(max(xb - RX + cq * 4, 0), W_ - 4);
        gload16(s0 + (gz * H_ + gy) * W_ + gx, &tile[lin * 4]);
    }

    // ---- flow dwordx4 x3 (uniform 3 vmem instrs per wave) ----
    const int xq = tid & 7;                // 8 x-quads
    const int ly = (tid >> 3) & 7;         // 8 y
    const int lz = tid >> 6;               // 8 z
    const int x0g = xb + xq * 4;
    const int y = yb + ly, z = zb + lz;
    const int sbase = (z * H_ + y) * W_ + x0g;
    const float4 fz4 = *(const float4*)(fb + sbase);
    const float4 fy4 = *(const float4*)(fb + S_ + sbase);
    const float4 fx4 = *(const float4*)(fb + 2 * S_ + sbase);

    __builtin_amdgcn_sched_barrier(0);   // pin: plane0 + flow issued above

    // ---- staging plane1: 4 unconditional DMA instrs per wave ----
#pragma unroll
    for (int j = 0; j < 4; ++j) {
        const int lin = j * NTHREADS + tid;
        const int row = lin / 10;
        const int cq  = lin - row * 10;
        const int rz = row / CY, ry = row - rz * CY;
        const int gz = min(max(zb - RZ + rz, 0), D_ - 1);
        const int gy = min(max(yb - RY + ry, 0), H_ - 1);
        const int gx = min(max(xb - RX + cq * 4, 0), W_ - 4);
        gload16(s0 + S_ + (gz * H_ + gy) * W_ + gx, &tile[PLANE_PAD + lin * 4]);
    }

    __builtin_amdgcn_sched_barrier(0);   // pin: plane1 issued above the wait

    // ---- phase A gate: plane0 + flow landed; plane1 (4 instrs) in flight
    asm volatile("s_waitcnt vmcnt(4)" ::: "memory");
    __builtin_amdgcn_sched_barrier(0);
    __builtin_amdgcn_s_barrier();
    __builtin_amdgcn_sched_barrier(0);

    const int zlo = max(0, zb - RZ), zhi = min(D_, zb + ZT + RZ);
    const int ylo = max(0, yb - RY), yhi = min(H_, yb + YT + RY);
    const int xlo = max(0, xb - RX), xhi = min(W_, xb + XT + RX);

    // ---- phase A: build state, compute ch0 (plane1 DMA hides under this)
    const PState st0 = mk_state(x0g + 0, y, z, fz4.x, fy4.x, fx4.x,
                                zb, yb, xb, zlo, zhi, ylo, yhi, xlo, xhi);
    const PState st1 = mk_state(x0g + 1, y, z, fz4.y, fy4.y, fx4.y,
                                zb, yb, xb, zlo, zhi, ylo, yhi, xlo, xhi);
    const PState st2 = mk_state(x0g + 2, y, z, fz4.z, fy4.z, fx4.z,
                                zb, yb, xb, zlo, zhi, ylo, yhi, xlo, xhi);
    const PState st3 = mk_state(x0g + 3, y, z, fz4.w, fy4.w, fx4.w,
                                zb, yb, xb, zlo, zhi, ylo, yhi, xlo, xhi);

    const float c0a = eval_ch(st0, tile, s0);
    const float c0b = eval_ch(st1, tile, s0);
    const float c0c = eval_ch(st2, tile, s0);
    const float c0d = eval_ch(st3, tile, s0);

    // ---- phase B gate: plane1 landed (waited BEFORE issuing the store)
    asm volatile("s_waitcnt vmcnt(0)" ::: "memory");
    __builtin_amdgcn_sched_barrier(0);
    *(float4*)(o0 + sbase) = make_float4(c0a, c0b, c0c, c0d);
    __builtin_amdgcn_s_barrier();
    __builtin_amdgcn_sched_barrier(0);

    // ---- phase B: ch1 = 8 LDS reads + blends, weights reused ----
    const float c1a = eval_ch(st0, tile + PLANE_PAD, s0 + S_);
    const float c1b = eval_ch(st1, tile + PLANE_PAD, s0 + S_);
    const float c1c = eval_ch(st2, tile + PLANE_PAD, s0 + S_);
    const float c1d = eval_ch(st3, tile + PLANE_PAD, s0 + S_);

    *(float4*)(o0 + S_ + sbase) = make_float4(c1a, c1b, c1c, c1d);
}

extern "C" void kernel_launch(void* const* d_in, const int* in_sizes, int n_in,
                              void* d_out, int out_size, void* d_ws, size_t ws_size,
                              hipStream_t stream) {
    const float* src  = (const float*)d_in[0];
    const float* flow = (const float*)d_in[1];
    float* out = (float*)d_out;

    // grid: x 4, y 20, z = 16 z-tiles x B2 = 32 -> 2560 blocks
    //     = 5 exact residency rounds at 2 blocks/CU (64 KB LDS).
    dim3 grid(W_ / XT, H_ / YT, (D_ / ZT) * B_);
    warp3d_tile<<<grid, NTHREADS, 0, stream>>>(src, flow, out);
}

// Round 11
// 177.726 us; speedup vs baseline: 1.0638x; 1.0638x over previous
//
#include <hip/hip_runtime.h>

// SpatialTransformer: 3D trilinear warp, zeros padding.
// src [B,C,D,H,W] f32 = [2,2,128,160,128]; flow [B,3,D,H,W]; out [B,C,D,H,W].
//
// R19: Z-MARCH DMA DOUBLE-BUFFER on the R16 structure (best: 56.4us).
// R18 post-mortem (94us, conflicts==0): fallback global loads issued AFTER
// an outstanding DMA drain it when consumed (vmcnt is IN-ORDER) -> the
// intra-tile channel seam was too short to hide anything, and sched_barrier
// fences strangled compute scheduling. The tile-to-tile seam is long:
//  - Each block owns an (xb,yb) column, marches NSTEP=4 z-tiles (ZCHUNK=32).
//  - Per step: issue stage(t+1) DMAs into the other buffer (8 uniform
//    DMAs/thread: buffer padded to 4096 chunks -> per-wave vmem count
//    exact), then vmcnt(11) = stage(t+1)+flow(t+1) left in flight ->
//    s_barrier -> compute tile t (R16 compute, fallback inline; its
//    mid-compute drains now land after most of stage(t+1)'s latency) ->
//    store -> s_barrier #2 (bufc not overwritten by stage(t+2) until all
//    waves finished reading it).
//  - LDS 2 x 64 KB = 128 KB -> dynamic LDS + hipFuncSetAttribute (not a
//    stream op; graph-capture safe). 1 block/CU x 8 waves; grid 640.
//  - Occupancy will read ~20-25% (8-wave ceiling): expected, not failure.
// Falsification pre-commit: clean (WRITE==40960KB, no spill) >= 54us ->
// tile-level overlap exhausted -> declare gather-latency wall.

#define B_ 2
#define C_ 2
#define D_ 128
#define H_ 160
#define W_ 128
constexpr int S_ = D_ * H_ * W_;

#define ZT 8
#define YT 8
#define XT 32
#define RZ 3
#define RY 3
#define RX 4
#define CZ (ZT + 2 * RZ)   // 14
#define CY (YT + 2 * RY)   // 14
#define CX (XT + 2 * RX)   // 40
#define NTHREADS 512
#define PLANE (CZ * CY * CX)        // 7840 floats per channel plane
#define CHPP (PLANE / 4)            // 1960 16B chunks per plane
#define BUFFL 16384                 // floats per buffer (64 KB incl phantom pad)
#define ZCHUNK 32
#define NSTEP (ZCHUNK / ZT)         // 4
#define ZSTRIDE (ZT * H_ * W_)      // flat-index advance per step

typedef const __attribute__((address_space(1))) unsigned int ga_u32;
typedef __attribute__((address_space(3))) unsigned int lds_u32;

__device__ __forceinline__ void gload16(const float* g, float* l) {
    // 16B global->LDS DMA; zero VGPR dest, vmcnt-tracked (in-order).
    __builtin_amdgcn_global_load_lds((ga_u32*)g, (lds_u32*)l, 16, 0, 0);
}

// Issue one tile's staging: 4096 chunks (3920 real + 176 phantom), exactly
// 8 DMA instrs per thread (uniform vmem count per wave). All addresses
// clamped in-bounds; phantom chunks land in the buffer's pad region.
__device__ __forceinline__ void stage_tile(const float* __restrict__ s0,
                                           float* __restrict__ buf,
                                           int zb, int yb, int xb, int tid)
{
#pragma unroll
    for (int j = 0; j < 8; ++j) {
        const int lin = j * NTHREADS + tid;      // 0..4095
        const int pl  = (lin >= CHPP) ? 1 : 0;
        const int rem = lin - pl * CHPP;         // phantom rows clamp to valid
        const int row = rem / 10;
        const int cq  = rem - row * 10;
        const int rz = row / CY, ry = row - rz * CY;
        const int gz = min(max(zb - RZ + rz, 0), D_ - 1);
        const int gy = min(max(yb - RY + ry, 0), H_ - 1);
        const int gx = min(max(xb - RX + cq * 4, 0), W_ - 4);
        gload16(s0 + pl * S_ + (gz * H_ + gy) * W_ + gx, &buf[lin * 4]);
    }
}

// One voxel-pair (both channels). buf = current tile buffer (2 planes).
__device__ __forceinline__ float2 compute_pair(
    int x, int y, int z, float fz, float fy, float fx,
    int zb, int yb, int xb,
    int zlo, int zhi, int ylo, int yhi, int xlo, int xhi,
    const float* __restrict__ buf, const float* __restrict__ s0)
{
    const float iz = (float)z + fz;
    const float iy = (float)y + fy;
    const float ix = (float)x + fx;

    const float zf = floorf(iz), yf = floorf(iy), xf = floorf(ix);
    const float tz = iz - zf, ty = iy - yf, tx = ix - xf;
    const int z0 = (int)zf, y0 = (int)yf, x0 = (int)xf;

    const int zc0 = min(max(z0, 0), D_ - 1), zc1 = min(max(z0 + 1, 0), D_ - 1);
    const int yc0 = min(max(y0, 0), H_ - 1), yc1 = min(max(y0 + 1, 0), H_ - 1);
    const int xp  = min(max(x0, 0), W_ - 2);

    const float wz0 = ((unsigned)z0       < (unsigned)D_) ? (1.f - tz) : 0.f;
    const float wz1 = ((unsigned)(z0 + 1) < (unsigned)D_) ? tz         : 0.f;
    const float wy0 = ((unsigned)y0       < (unsigned)H_) ? (1.f - ty) : 0.f;
    const float wy1 = ((unsigned)(y0 + 1) < (unsigned)H_) ? ty         : 0.f;
    const float wx0 = ((unsigned)x0       < (unsigned)W_) ? (1.f - tx) : 0.f;
    const float wx1 = ((unsigned)(x0 + 1) < (unsigned)W_) ? tx         : 0.f;
    const bool hi0 = x0 > xp;   // x0 == W-1
    const bool lo1 = x0 < xp;   // x0 == -1

    const bool fast = (zc0 >= zlo) & (zc1 < zhi) &
                      (yc0 >= ylo) & (yc1 < yhi) &
                      (xp >= xlo) & (xp + 1 < xhi);

    float acc0, acc1;
    if (fast) {
        const int izl0 = zc0 - (zb - RZ), izl1 = zc1 - (zb - RZ);
        const int iyl0 = yc0 - (yb - RY), iyl1 = yc1 - (yb - RY);
        const int ixl  = xp - (xb - RX);
        const int o00 = (izl0 * CY + iyl0) * CX + ixl;
        const int o01 = (izl0 * CY + iyl1) * CX + ixl;
        const int o10 = (izl1 * CY + iyl0) * CX + ixl;
        const int o11 = (izl1 * CY + iyl1) * CX + ixl;
        const float a00 = buf[o00],         b00 = buf[o00 + 1];
        const float a01 = buf[o01],         b01 = buf[o01 + 1];
        const float a10 = buf[o10],         b10 = buf[o10 + 1];
        const float a11 = buf[o11],         b11 = buf[o11 + 1];
        const float c00 = buf[PLANE + o00], d00 = buf[PLANE + o00 + 1];
        const float c01 = buf[PLANE + o01], d01 = buf[PLANE + o01 + 1];
        const float c10 = buf[PLANE + o10], d10 = buf[PLANE + o10 + 1];
        const float c11 = buf[PLANE + o11], d11 = buf[PLANE + o11 + 1];
        const float q00 = wx0 * (hi0 ? b00 : a00) + wx1 * (lo1 ? a00 : b00);
        const float q01 = wx0 * (hi0 ? b01 : a01) + wx1 * (lo1 ? a01 : b01);
        const float q10 = wx0 * (hi0 ? b10 : a10) + wx1 * (lo1 ? a10 : b10);
        const float q11 = wx0 * (hi0 ? b11 : a11) + wx1 * (lo1 ? a11 : b11);
        const float r00 = wx0 * (hi0 ? d00 : c00) + wx1 * (lo1 ? c00 : d00);
        const float r01 = wx0 * (hi0 ? d01 : c01) + wx1 * (lo1 ? c01 : d01);
        const float r10 = wx0 * (hi0 ? d10 : c10) + wx1 * (lo1 ? c10 : d10);
        const float r11 = wx0 * (hi0 ? d11 : c11) + wx1 * (lo1 ? c11 : d11);
        acc0 = wz0 * (wy0 * q00 + wy1 * q01) + wz1 * (wy0 * q10 + wy1 * q11);
        acc1 = wz0 * (wy0 * r00 + wy1 * r01) + wz1 * (wy0 * r10 + wy1 * r11);
    } else {
        const int l00 = (zc0 * H_ + yc0) * W_ + xp;
        const int l01 = (zc0 * H_ + yc1) * W_ + xp;
        const int l10 = (zc1 * H_ + yc0) * W_ + xp;
        const int l11 = (zc1 * H_ + yc1) * W_ + xp;
        const float a00 = s0[l00],      b00 = s0[l00 + 1];
        const float a01 = s0[l01],      b01 = s0[l01 + 1];
        const float a10 = s0[l10],      b10 = s0[l10 + 1];
        const float a11 = s0[l11],      b11 = s0[l11 + 1];
        const float c00 = s0[S_ + l00], d00 = s0[S_ + l00 + 1];
        const float c01 = s0[S_ + l01], d01 = s0[S_ + l01 + 1];
        const float c10 = s0[S_ + l10], d10 = s0[S_ + l10 + 1];
        const float c11 = s0[S_ + l11], d11 = s0[S_ + l11 + 1];
        const float q00 = wx0 * (hi0 ? b00 : a00) + wx1 * (lo1 ? a00 : b00);
        const float q01 = wx0 * (hi0 ? b01 : a01) + wx1 * (lo1 ? a01 : b01);
        const float q10 = wx0 * (hi0 ? b10 : a10) + wx1 * (lo1 ? a10 : b10);
        const float q11 = wx0 * (hi0 ? b11 : a11) + wx1 * (lo1 ? a11 : b11);
        const float r00 = wx0 * (hi0 ? d00 : c00) + wx1 * (lo1 ? c00 : d00);
        const float r01 = wx0 * (hi0 ? d01 : c01) + wx1 * (lo1 ? c01 : d01);
        const float r10 = wx0 * (hi0 ? d10 : c10) + wx1 * (lo1 ? c10 : d10);
        const float r11 = wx0 * (hi0 ? d11 : c11) + wx1 * (lo1 ? c11 : d11);
        acc0 = wz0 * (wy0 * q00 + wy1 * q01) + wz1 * (wy0 * q10 + wy1 * q11);
        acc1 = wz0 * (wy0 * r00 + wy1 * r01) + wz1 * (wy0 * r10 + wy1 * r11);
    }
    return make_float2(acc0, acc1);
}

__global__ __launch_bounds__(NTHREADS, 2) void warp3d_march(
    const float* __restrict__ src,
    const float* __restrict__ flow,
    float* __restrict__ out)
{
    extern __shared__ float tile[];   // 2 * BUFFL floats = 128 KB

    const int tid = threadIdx.x;
    const int xb = blockIdx.x * XT;
    const int yb = blockIdx.y * YT;
    const int bz = blockIdx.z;
    const int zb0 = (bz & 3) * ZCHUNK;     // 4 z-chunks
    const int b   = bz >> 2;               // batch

    const float* fb = flow + (long long)b * 3 * S_;
    const float* s0 = src + (long long)b * C_ * S_;   // ch0; ch1 = s0 + S_
    float* o0       = out + (long long)b * C_ * S_;

    const int xq = tid & 7;                // 8 x-quads
    const int ly = (tid >> 3) & 7;         // 8 y
    const int lz = tid >> 6;               // 8 z
    const int x0g = xb + xq * 4;
    const int y = yb + ly;
    int z = zb0 + lz;
    int sbase = (z * H_ + y) * W_ + x0g;

    const int ylo = max(0, yb - RY), yhi = min(H_, yb + YT + RY);
    const int xlo = max(0, xb - RX), xhi = min(W_, xb + XT + RX);

    // ---- prologue: stage tile 0 + flow 0 (11 vmem ops/wave in flight) ----
    stage_tile(s0, tile, zb0, yb, xb, tid);
    float4 fzc = *(const float4*)(fb + sbase);
    float4 fyc = *(const float4*)(fb + S_ + sbase);
    float4 fxc = *(const float4*)(fb + 2 * S_ + sbase);

#pragma unroll 1
    for (int t = 0; t < NSTEP; ++t) {
        const int zb = zb0 + t * ZT;
        const bool more = (t + 1 < NSTEP);
        const float* bufc = tile + (t & 1) * BUFFL;
        float* bufn       = tile + ((t + 1) & 1) * BUFFL;

        // ---- issue next-tile stage + flow (flow unconditional, clamped) ----
        if (more) stage_tile(s0, bufn, zb + ZT, yb, xb, tid);
        const int sbn = sbase + (more ? ZSTRIDE : 0);
        const float4 fzn = *(const float4*)(fb + sbn);
        const float4 fyn = *(const float4*)(fb + S_ + sbn);
        const float4 fxn = *(const float4*)(fb + 2 * S_ + sbn);

        // ---- gate: stage(t)+flow(t)+stores(t-1) drained; next stage in flight
        __builtin_amdgcn_sched_barrier(0);
        if (more) { asm volatile("s_waitcnt vmcnt(11)" ::: "memory"); }
        else      { asm volatile("s_waitcnt vmcnt(0)"  ::: "memory"); }
        __builtin_amdgcn_sched_barrier(0);
        __builtin_amdgcn_s_barrier();      // #1: all waves' stage(t) landed
        __builtin_amdgcn_sched_barrier(0);

        // ---- compute tile t ----
        const int zlo = max(0, zb - RZ), zhi = min(D_, zb + ZT + RZ);

        const float2 v0 = compute_pair(x0g + 0, y, z, fzc.x, fyc.x, fxc.x,
                                       zb, yb, xb, zlo, zhi, ylo, yhi, xlo, xhi, bufc, s0);
        const float2 v1 = compute_pair(x0g + 1, y, z, fzc.y, fyc.y, fxc.y,
                                       zb, yb, xb, zlo, zhi, ylo, yhi, xlo, xhi, bufc, s0);
        const float2 v2 = compute_pair(x0g + 2, y, z, fzc.z, fyc.z, fxc.z,
                                       zb, yb, xb, zlo, zhi, ylo, yhi, xlo, xhi, bufc, s0);
        const float2 v3 = compute_pair(x0g + 3, y, z, fzc.w, fyc.w, fxc.w,
                                       zb, yb, xb, zlo, zhi, ylo, yhi, xlo, xhi, bufc, s0);

        *(float4*)(o0 + sbase)      = make_float4(v0.x, v1.x, v2.x, v3.x);
        *(float4*)(o0 + S_ + sbase) = make_float4(v0.y, v1.y, v2.y, v3.y);

        __builtin_amdgcn_s_barrier();      // #2: bufc free before stage(t+2)
        __builtin_amdgcn_sched_barrier(0);

        // ---- roll state ----
        fzc = fzn; fyc = fyn; fxc = fxn;
        sbase = sbn; z += ZT;
    }
}

extern "C" void kernel_launch(void* const* d_in, const int* in_sizes, int n_in,
                              void* d_out, int out_size, void* d_ws, size_t ws_size,
                              hipStream_t stream) {
    const float* src  = (const float*)d_in[0];
    const float* flow = (const float*)d_in[1];
    float* out = (float*)d_out;

    static bool attr_set = false;
    if (!attr_set) {
        hipFuncSetAttribute(reinterpret_cast<const void*>(warp3d_march),
                            hipFuncAttributeMaxDynamicSharedMemorySize,
                            2 * BUFFL * (int)sizeof(float));
        attr_set = true;
    }

    // grid: x 4, y 20, z = 4 z-chunks x B2 = 8 -> 640 blocks, 1 block/CU.
    dim3 grid(W_ / XT, H_ / YT, (D_ / ZCHUNK) * B_);
    warp3d_march<<<grid, NTHREADS, 2 * BUFFL * sizeof(float), stream>>>(src, flow, out);
}

// Round 12
// 164.597 us; speedup vs baseline: 1.1487x; 1.0798x over previous
//
#include <hip/hip_runtime.h>

// SpatialTransformer: 3D trilinear warp, zeros padding.
// src [B,C,D,H,W] f32 = [2,2,128,160,128]; flow [B,3,D,H,W]; out [B,C,D,H,W].
//
// R20: DRAIN-SAFE Z-MARCH. R18/R19 both died to the same law: vmcnt is
// IN-ORDER, so any global load issued after the stage(t+1) DMA burst that
// is consumed before the next gate drains the burst (72% of waves have a
// fallback pair -> overlap destroyed). Fix: resolve fallback BEFORE the
// burst. Per step:
//   1. mk_state from flow(t) regs (auto-waitcnt here drains THIS wave's
//      stage(t), which had all of compute(t-1) to land)
//   2. fallback pairs (rare, divergent) resolved from GLOBAL now (needs
//      no LDS; drains only old stores)
//   3. issue stage(t+1): 9 uniform DMAs/thread (phantoms ALIAS chunks
//      0..127 -> dup addresses = cache hits, no extra HBM; fixes R19's
//      fetch bloat) + flow(t+1) prefetch (15 uniform loads)
//   4. s_waitcnt vmcnt(24) = exactly stage(t+1)+flow(t+1) left in flight
//      (older variable-count fallback is fine: vmcnt waits "until <=N")
//   5. raw s_barrier (no vmcnt(0)!) -> fast compute touches LDS ONLY ->
//      stores -> barrier #2 (protects bufc from stage(t+2)).
// Geometry: YT=10, ZCHUNK=64, NSTEP=8 -> grid 4x16x4 = 256 blocks =
// EXACTLY 1/CU, one dispatch round, zero tail; prologue stage exposed
// once per 8 tiles. LDS 2 x 72 KB = 144 KB dynamic. 5 pairs/thread, all
// arrays indexed only in #pragma unroll constant-trip loops (rule #20).
// Spill tripwire: WRITE_SIZE must stay 40960 KB. Falsification: clean
// >= 54us -> compute-phase wall -> revert to R16 and declare.

#define B_ 2
#define C_ 2
#define D_ 128
#define H_ 160
#define W_ 128
constexpr int S_ = D_ * H_ * W_;

#define ZT 8
#define YT 10
#define XT 32
#define RZ 3
#define RY 3
#define RX 4
#define CZ (ZT + 2 * RZ)        // 14
#define CY (YT + 2 * RY)        // 16
#define CX (XT + 2 * RX)        // 40
#define NTHREADS 512
#define PLANE (CZ * CY * CX)    // 8960 floats per channel plane
#define CHPP (PLANE / 4)        // 2240 16B chunks per plane
#define NCHUNK (2 * CHPP)       // 4480 real chunks
#define NPAD (9 * NTHREADS)     // 4608 issued chunks (128 phantom-alias)
#define BUFFL (NPAD * 4)        // 18432 floats = 72 KB per buffer
#define ZCHUNK 64
#define NSTEP 8
#define ZSTRIDE (ZT * H_ * W_)
#define PAIRS 5

typedef const __attribute__((address_space(1))) unsigned int ga_u32;
typedef __attribute__((address_space(3))) unsigned int lds_u32;

__device__ __forceinline__ void gload16(const float* g, float* l) {
    // 16B global->LDS DMA; zero VGPR dest, vmcnt-tracked (in-order).
    __builtin_amdgcn_global_load_lds((ga_u32*)g, (lds_u32*)l, 16, 0, 0);
}

// Issue one tile's staging: exactly 9 DMA instrs/thread (uniform per-wave
// vmem count). Phantom chunks (lin >= 4480) alias real chunks 0..127:
// duplicate source addresses (cache hits), distinct pad destinations.
__device__ __forceinline__ void stage_tile(const float* __restrict__ s0,
                                           float* __restrict__ buf,
                                           int zb, int yb, int xb, int tid)
{
#pragma unroll
    for (int j = 0; j < 9; ++j) {
        const int lin = j * NTHREADS + tid;              // 0..4607
        const int r   = (lin < NCHUNK) ? lin : (lin - NCHUNK);  // alias
        const int pl  = (r >= CHPP) ? 1 : 0;
        const int rem = r - pl * CHPP;                   // 0..2239
        const int row = rem / 10;                        // 0..223
        const int cq  = rem - row * 10;                  // x-quad 0..9
        const int rz = row >> 4, ry = row & 15;          // CY = 16
        const int gz = min(max(zb - RZ + rz, 0), D_ - 1);
        const int gy = min(max(yb - RY + ry, 0), H_ - 1);
        const int gx = min(max(xb - RX + cq * 4, 0), W_ - 4);
        gload16(s0 + pl * S_ + (gz * H_ + gy) * W_ + gx, &buf[lin * 4]);
    }
}

// Per-pair cross-phase state. Accessed via named/unrolled indices only.
struct PState {
    int o00, o01, o10, o11;              // LDS offsets (fast) or global idx
    float w00, w01, w10, w11, wx0, wx1;  // combined z*y weights + x weights
    bool hi0, lo1, fast;
};

__device__ __forceinline__ PState mk_state(
    int x, int y, int z, float fz, float fy, float fx,
    int zb, int yb, int xb,
    int zlo, int zhi, int ylo, int yhi, int xlo, int xhi)
{
    const float iz = (float)z + fz;
    const float iy = (float)y + fy;
    const float ix = (float)x + fx;

    const float zf = floorf(iz), yf = floorf(iy), xf = floorf(ix);
    const float tz = iz - zf, ty = iy - yf, tx = ix - xf;
    const int z0 = (int)zf, y0 = (int)yf, x0 = (int)xf;

    const int zc0 = min(max(z0, 0), D_ - 1), zc1 = min(max(z0 + 1, 0), D_ - 1);
    const int yc0 = min(max(y0, 0), H_ - 1), yc1 = min(max(y0 + 1, 0), H_ - 1);
    const int xp  = min(max(x0, 0), W_ - 2);

    const float wz0 = ((unsigned)z0       < (unsigned)D_) ? (1.f - tz) : 0.f;
    const float wz1 = ((unsigned)(z0 + 1) < (unsigned)D_) ? tz         : 0.f;
    const float wy0 = ((unsigned)y0       < (unsigned)H_) ? (1.f - ty) : 0.f;
    const float wy1 = ((unsigned)(y0 + 1) < (unsigned)H_) ? ty         : 0.f;

    PState st;
    st.wx0 = ((unsigned)x0       < (unsigned)W_) ? (1.f - tx) : 0.f;
    st.wx1 = ((unsigned)(x0 + 1) < (unsigned)W_) ? tx         : 0.f;
    st.hi0 = x0 > xp;   // x0 == W-1
    st.lo1 = x0 < xp;   // x0 == -1
    st.w00 = wz0 * wy0; st.w01 = wz0 * wy1;
    st.w10 = wz1 * wy0; st.w11 = wz1 * wy1;
    st.fast = (zc0 >= zlo) & (zc1 < zhi) &
              (yc0 >= ylo) & (yc1 < yhi) &
              (xp >= xlo) & (xp + 1 < xhi);
    if (st.fast) {
        const int izl0 = zc0 - (zb - RZ), izl1 = zc1 - (zb - RZ);
        const int iyl0 = yc0 - (yb - RY), iyl1 = yc1 - (yb - RY);
        const int ixl  = xp - (xb - RX);
        st.o00 = (izl0 * CY + iyl0) * CX + ixl;
        st.o01 = (izl0 * CY + iyl1) * CX + ixl;
        st.o10 = (izl1 * CY + iyl0) * CX + ixl;
        st.o11 = (izl1 * CY + iyl1) * CX + ixl;
    } else {
        st.o00 = (zc0 * H_ + yc0) * W_ + xp;
        st.o01 = (zc0 * H_ + yc1) * W_ + xp;
        st.o10 = (zc1 * H_ + yc0) * W_ + xp;
        st.o11 = (zc1 * H_ + yc1) * W_ + xp;
    }
    return st;
}

// One channel from saved state; p = LDS plane (fast) or global base.
__device__ __forceinline__ float eval_any(const PState& st, const float* p)
{
    const float a00 = p[st.o00], b00 = p[st.o00 + 1];
    const float a01 = p[st.o01], b01 = p[st.o01 + 1];
    const float a10 = p[st.o10], b10 = p[st.o10 + 1];
    const float a11 = p[st.o11], b11 = p[st.o11 + 1];
    const float q00 = st.wx0 * (st.hi0 ? b00 : a00) + st.wx1 * (st.lo1 ? a00 : b00);
    const float q01 = st.wx0 * (st.hi0 ? b01 : a01) + st.wx1 * (st.lo1 ? a01 : b01);
    const float q10 = st.wx0 * (st.hi0 ? b10 : a10) + st.wx1 * (st.lo1 ? a10 : b10);
    const float q11 = st.wx0 * (st.hi0 ? b11 : a11) + st.wx1 * (st.lo1 ? a11 : b11);
    return st.w00 * q00 + st.w01 * q01 + st.w10 * q10 + st.w11 * q11;
}

__global__ __launch_bounds__(NTHREADS, 2) void warp3d_march(
    const float* __restrict__ src,
    const float* __restrict__ flow,
    float* __restrict__ out)
{
    extern __shared__ float tile[];   // 2 * BUFFL = 144 KB

    const int tid = threadIdx.x;
    const int xb = blockIdx.x * XT;
    const int yb = blockIdx.y * YT;
    const int bz = blockIdx.z;
    const int zc = (bz & 1) * ZCHUNK;      // 2 z-chunks
    const int b  = bz >> 1;                // batch

    const float* fb = flow + (long long)b * 3 * S_;
    const float* s0 = src + (long long)b * C_ * S_;   // ch0; ch1 = s0 + S_
    float* o0       = out + (long long)b * C_ * S_;

    // ---- per-pair coords: vox = k*512+tid over 8z x 10y x 32x ----
    int lxk[PAIRS], lyk[PAIRS], lzk[PAIRS], sk[PAIRS];
#pragma unroll
    for (int k = 0; k < PAIRS; ++k) {
        const int vox = k * NTHREADS + tid;
        lxk[k] = vox & 31;
        const int r = vox >> 5;            // 0..79
        lyk[k] = r % 10;
        lzk[k] = r / 10;
        sk[k] = ((zc + lzk[k]) * H_ + yb + lyk[k]) * W_ + xb + lxk[k];
    }

    const int ylo = max(0, yb - RY), yhi = min(H_, yb + YT + RY);
    const int xlo = max(0, xb - RX), xhi = min(W_, xb + XT + RX);

    // ---- prologue: stage tile 0, prefetch flow 0 ----
    stage_tile(s0, tile, zc, yb, xb, tid);
    float fzc[PAIRS], fyc[PAIRS], fxc[PAIRS];
#pragma unroll
    for (int k = 0; k < PAIRS; ++k) {
        fzc[k] = fb[sk[k]];
        fyc[k] = fb[S_ + sk[k]];
        fxc[k] = fb[2 * S_ + sk[k]];
    }

#pragma unroll 1
    for (int t = 0; t < NSTEP; ++t) {
        __builtin_amdgcn_sched_barrier(0);
        const int zb = zc + t * ZT;
        const bool more = (t + 1 < NSTEP);
        const float* bufc = tile + (t & 1) * BUFFL;
        float* bufn       = tile + ((t + 1) & 1) * BUFFL;
        const int zlo = max(0, zb - RZ), zhi = min(D_, zb + ZT + RZ);

        // 1. states from flow(t). First flow-reg use auto-drains this
        //    wave's stage(t) (in-order vmcnt) -- it had all of compute(t-1).
        PState st[PAIRS];
        float a0[PAIRS], a1[PAIRS];
#pragma unroll
        for (int k = 0; k < PAIRS; ++k)
            st[k] = mk_state(xb + lxk[k], yb + lyk[k], zb + lzk[k],
                             fzc[k], fyc[k], fxc[k],
                             zb, yb, xb, zlo, zhi, ylo, yhi, xlo, xhi);

        // 2. fallback pairs resolved from GLOBAL now (before the burst).
#pragma unroll
        for (int k = 0; k < PAIRS; ++k)
            if (!st[k].fast) {
                a0[k] = eval_any(st[k], s0);
                a1[k] = eval_any(st[k], s0 + S_);
            }
        __builtin_amdgcn_sched_barrier(0);

        // 3. burst: stage(t+1) 9 DMAs + flow(t+1) 15 loads (all uniform).
        if (more) stage_tile(s0, bufn, zb + ZT, yb, xb, tid);
        float fzn[PAIRS], fyn[PAIRS], fxn[PAIRS];
        int sn[PAIRS];
#pragma unroll
        for (int k = 0; k < PAIRS; ++k) {
            sn[k] = sk[k] + (more ? ZSTRIDE : 0);   // last iter: reload (L1)
            fzn[k] = fb[sn[k]];
            fyn[k] = fb[S_ + sn[k]];
            fxn[k] = fb[2 * S_ + sn[k]];
        }
        __builtin_amdgcn_sched_barrier(0);

        // 4. gate: leave exactly the burst in flight; drain older.
        if (more) { asm volatile("s_waitcnt vmcnt(24)" ::: "memory"); }
        else      { asm volatile("s_waitcnt vmcnt(15)" ::: "memory"); }
        __builtin_amdgcn_sched_barrier(0);
        __builtin_amdgcn_s_barrier();      // all waves' stage(t) landed
        __builtin_amdgcn_sched_barrier(0);

        // 5. fast compute: LDS ONLY -- nothing here consumes global.
#pragma unroll
        for (int k = 0; k < PAIRS; ++k)
            if (st[k].fast) {
                a0[k] = eval_any(st[k], bufc);
                a1[k] = eval_any(st[k], bufc + PLANE);
            }

        // 6. stores (fire-and-forget; drained by next iter's step 2/4).
#pragma unroll
        for (int k = 0; k < PAIRS; ++k) {
            o0[sk[k]]      = a0[k];
            o0[S_ + sk[k]] = a1[k];
        }

        __builtin_amdgcn_s_barrier();      // bufc free before stage(t+2)
        __builtin_amdgcn_sched_barrier(0);

        // roll flow state
#pragma unroll
        for (int k = 0; k < PAIRS; ++k) {
            fzc[k] = fzn[k]; fyc[k] = fyn[k]; fxc[k] = fxn[k]; sk[k] = sn[k];
        }
    }
}

extern "C" void kernel_launch(void* const* d_in, const int* in_sizes, int n_in,
                              void* d_out, int out_size, void* d_ws, size_t ws_size,
                              hipStream_t stream) {
    const float* src  = (const float*)d_in[0];
    const float* flow = (const float*)d_in[1];
    float* out = (float*)d_out;

    static bool attr_set = false;
    if (!attr_set) {
        hipFuncSetAttribute(reinterpret_cast<const void*>(warp3d_march),
                            hipFuncAttributeMaxDynamicSharedMemorySize,
                            2 * BUFFL * (int)sizeof(float));
        attr_set = true;
    }

    // grid: x 4, y 16 (YT=10), z = 2 z-chunks x B2 = 4 -> 256 blocks
    //     = EXACTLY 1 per CU, one dispatch round, zero tail.
    dim3 grid(W_ / XT, H_ / YT, (D_ / ZCHUNK) * B_);
    warp3d_march<<<grid, NTHREADS, 2 * BUFFL * sizeof(float), stream>>>(src, flow, out);
}

// Round 13
// 155.549 us; speedup vs baseline: 1.2155x; 1.0582x over previous
//
#include <hip/hip_runtime.h>

// SpatialTransformer: 3D trilinear warp, zeros padding.
// src [B,C,D,H,W] f32 = [2,2,128,160,128]; flow [B,3,D,H,W]; out [B,C,D,H,W].
//
// R21: CONSECUTIVE-X LANES on the R16 structure (best: 56.4us).
// R20 post-mortem: drain-safe overlap at 1 block/CU = 69.8us clean ->
// tile-level overlap is not the lever. Costing R16's compute phase found
// the real residual: 6.86M conflict cycles = ~10.5 extra cyc per
// ds_read2_b32 (~8-way). Cause: the x-QUAD thread map makes every lane
// address = 4*xq + 8*ly + jitter == 0 (mod 4) -> 64 lanes on 8 banks.
// (R15's pad test kept the quad map -> never tested this; confounded.)
// Fix (ONLY change vs R16): lx = tid&31 consecutive x, ly=(tid>>5)&7,
// z-half = tid>>8, 4 pairs/thread stepped in z. Lane bank =
// (x + 8*y) mod 32 -> exactly 2 lanes/bank = free (m136). Flow/out are
// scalar but perfectly coalesced (R15 proved dwordx4 bought nothing).
// Staging DMA, layout, barrier, grid identical to R16.
// Prediction: conflicts 6.86M -> <=2M; dur 56.4 -> 48-53us.
// Pre-commit: conflicts drop but dur >=55 -> latency-hidden -> declare.

#define B_ 2
#define C_ 2
#define D_ 128
#define H_ 160
#define W_ 128
constexpr int S_ = D_ * H_ * W_;

#define ZT 8
#define YT 8
#define XT 32
#define RZ 3
#define RY 3
#define RX 4
#define CZ (ZT + 2 * RZ)   // 14
#define CY (YT + 2 * RY)   // 14
#define CX (XT + 2 * RX)   // 40
#define NTHREADS 512
#define PLANE (CZ * CY * CX)        // 7840 floats per channel plane
#define CHPP (PLANE / 4)            // 1960 16B chunks per plane
#define NCHUNK_TOT (2 * CHPP)       // 3920 chunks total

typedef const __attribute__((address_space(1))) unsigned int ga_u32;
typedef __attribute__((address_space(3))) unsigned int lds_u32;

__device__ __forceinline__ void gload16(const float* g, float* l) {
    // 16B global -> LDS DMA; zero VGPR dest, vmcnt-tracked.
    __builtin_amdgcn_global_load_lds((ga_u32*)g, (lds_u32*)l, 16, 0, 0);
}

// One voxel-pair (both channels). tile = 2 planes of [CZ][CY][CX].
__device__ __forceinline__ float2 compute_pair(
    int x, int y, int z, float fz, float fy, float fx,
    int zb, int yb, int xb,
    int zlo, int zhi, int ylo, int yhi, int xlo, int xhi,
    const float* __restrict__ tile, const float* __restrict__ s0)
{
    const float iz = (float)z + fz;
    const float iy = (float)y + fy;
    const float ix = (float)x + fx;

    const float zf = floorf(iz), yf = floorf(iy), xf = floorf(ix);
    const float tz = iz - zf, ty = iy - yf, tx = ix - xf;
    const int z0 = (int)zf, y0 = (int)yf, x0 = (int)xf;

    const int zc0 = min(max(z0, 0), D_ - 1), zc1 = min(max(z0 + 1, 0), D_ - 1);
    const int yc0 = min(max(y0, 0), H_ - 1), yc1 = min(max(y0 + 1, 0), H_ - 1);
    const int xp  = min(max(x0, 0), W_ - 2);

    const float wz0 = ((unsigned)z0       < (unsigned)D_) ? (1.f - tz) : 0.f;
    const float wz1 = ((unsigned)(z0 + 1) < (unsigned)D_) ? tz         : 0.f;
    const float wy0 = ((unsigned)y0       < (unsigned)H_) ? (1.f - ty) : 0.f;
    const float wy1 = ((unsigned)(y0 + 1) < (unsigned)H_) ? ty         : 0.f;
    const float wx0 = ((unsigned)x0       < (unsigned)W_) ? (1.f - tx) : 0.f;
    const float wx1 = ((unsigned)(x0 + 1) < (unsigned)W_) ? tx         : 0.f;
    const bool hi0 = x0 > xp;   // x0 == W-1
    const bool lo1 = x0 < xp;   // x0 == -1

    const bool fast = (zc0 >= zlo) & (zc1 < zhi) &
                      (yc0 >= ylo) & (yc1 < yhi) &
                      (xp >= xlo) & (xp + 1 < xhi);

    float acc0, acc1;
    if (fast) {
        const int izl0 = zc0 - (zb - RZ), izl1 = zc1 - (zb - RZ);
        const int iyl0 = yc0 - (yb - RY), iyl1 = yc1 - (yb - RY);
        const int ixl  = xp - (xb - RX);
        const int o00 = (izl0 * CY + iyl0) * CX + ixl;
        const int o01 = (izl0 * CY + iyl1) * CX + ixl;
        const int o10 = (izl1 * CY + iyl0) * CX + ixl;
        const int o11 = (izl1 * CY + iyl1) * CX + ixl;
        const float a00 = tile[o00],         b00 = tile[o00 + 1];
        const float a01 = tile[o01],         b01 = tile[o01 + 1];
        const float a10 = tile[o10],         b10 = tile[o10 + 1];
        const float a11 = tile[o11],         b11 = tile[o11 + 1];
        const float c00 = tile[PLANE + o00], d00 = tile[PLANE + o00 + 1];
        const float c01 = tile[PLANE + o01], d01 = tile[PLANE + o01 + 1];
        const float c10 = tile[PLANE + o10], d10 = tile[PLANE + o10 + 1];
        const float c11 = tile[PLANE + o11], d11 = tile[PLANE + o11 + 1];
        const float q00 = wx0 * (hi0 ? b00 : a00) + wx1 * (lo1 ? a00 : b00);
        const float q01 = wx0 * (hi0 ? b01 : a01) + wx1 * (lo1 ? a01 : b01);
        const float q10 = wx0 * (hi0 ? b10 : a10) + wx1 * (lo1 ? a10 : b10);
        const float q11 = wx0 * (hi0 ? b11 : a11) + wx1 * (lo1 ? a11 : b11);
        const float r00 = wx0 * (hi0 ? d00 : c00) + wx1 * (lo1 ? c00 : d00);
        const float r01 = wx0 * (hi0 ? d01 : c01) + wx1 * (lo1 ? c01 : d01);
        const float r10 = wx0 * (hi0 ? d10 : c10) + wx1 * (lo1 ? c10 : d10);
        const float r11 = wx0 * (hi0 ? d11 : c11) + wx1 * (lo1 ? c11 : d11);
        acc0 = wz0 * (wy0 * q00 + wy1 * q01) + wz1 * (wy0 * q10 + wy1 * q11);
        acc1 = wz0 * (wy0 * r00 + wy1 * r01) + wz1 * (wy0 * r10 + wy1 * r11);
    } else {
        const int l00 = (zc0 * H_ + yc0) * W_ + xp;
        const int l01 = (zc0 * H_ + yc1) * W_ + xp;
        const int l10 = (zc1 * H_ + yc0) * W_ + xp;
        const int l11 = (zc1 * H_ + yc1) * W_ + xp;
        const float a00 = s0[l00],      b00 = s0[l00 + 1];
        const float a01 = s0[l01],      b01 = s0[l01 + 1];
        const float a10 = s0[l10],      b10 = s0[l10 + 1];
        const float a11 = s0[l11],      b11 = s0[l11 + 1];
        const float c00 = s0[S_ + l00], d00 = s0[S_ + l00 + 1];
        const float c01 = s0[S_ + l01], d01 = s0[S_ + l01 + 1];
        const float c10 = s0[S_ + l10], d10 = s0[S_ + l10 + 1];
        const float c11 = s0[S_ + l11], d11 = s0[S_ + l11 + 1];
        const float q00 = wx0 * (hi0 ? b00 : a00) + wx1 * (lo1 ? a00 : b00);
        const float q01 = wx0 * (hi0 ? b01 : a01) + wx1 * (lo1 ? a01 : b01);
        const float q10 = wx0 * (hi0 ? b10 : a10) + wx1 * (lo1 ? a10 : b10);
        const float q11 = wx0 * (hi0 ? b11 : a11) + wx1 * (lo1 ? a11 : b11);
        const float r00 = wx0 * (hi0 ? d00 : c00) + wx1 * (lo1 ? c00 : d00);
        const float r01 = wx0 * (hi0 ? d01 : c01) + wx1 * (lo1 ? c01 : d01);
        const float r10 = wx0 * (hi0 ? d10 : c10) + wx1 * (lo1 ? c10 : d10);
        const float r11 = wx0 * (hi0 ? d11 : c11) + wx1 * (lo1 ? c11 : d11);
        acc0 = wz0 * (wy0 * q00 + wy1 * q01) + wz1 * (wy0 * q10 + wy1 * q11);
        acc1 = wz0 * (wy0 * r00 + wy1 * r01) + wz1 * (wy0 * r10 + wy1 * r11);
    }
    return make_float2(acc0, acc1);
}

__global__ __launch_bounds__(NTHREADS, 4) void warp3d_tile(
    const float* __restrict__ src,
    const float* __restrict__ flow,
    float* __restrict__ out)
{
    __shared__ float tile[2 * PLANE];   // 15680 floats = 61.25 KB

    const int tid = threadIdx.x;
    const int xb = blockIdx.x * XT;
    const int yb = blockIdx.y * YT;
    const int bz = blockIdx.z;
    const int zb = (bz & 15) * ZT;         // 16 z-tiles
    const int b  = bz >> 4;                // batch

    const float* fb = flow + (long long)b * 3 * S_;
    const float* s0 = src + (long long)b * C_ * S_;   // ch0; ch1 = s0 + S_
    float* o0       = out + (long long)b * C_ * S_;

    // ---- staging: 3920 x 16B DMA chunks, zero VGPR dest, all clamped ----
#pragma unroll
    for (int j = 0; j < 8; ++j) {
        const int lin = j * NTHREADS + tid;
        if (lin < NCHUNK_TOT) {                // folds away for j < 7
            const int pl  = (lin >= CHPP) ? 1 : 0;
            const int rem = lin - pl * CHPP;
            const int row = rem / 10;          // rz*CY+ry, 0..195
            const int cq  = rem - row * 10;    // x-quad 0..9
            const int rz = row / CY, ry = row - rz * CY;
            const int gz = min(max(zb - RZ + rz, 0), D_ - 1);
            const int gy = min(max(yb - RY + ry, 0), H_ - 1);
            const int gx = min(max(xb - RX + cq * 4, 0), W_ - 4);
            gload16(s0 + pl * S_ + (gz * H_ + gy) * W_ + gx, &tile[lin * 4]);
        }
    }

    // ---- consecutive-x lane map: bank = (x + 8y) mod 32 -> 2-way max ----
    const int lx  = tid & 31;              // consecutive x across the wave
    const int ly  = (tid >> 5) & 7;        // 8 y
    const int lzh = tid >> 8;              // z-half 0..1
    const int x = xb + lx, y = yb + ly;
    const int z0g = zb + lzh * 4;          // this thread's 4 pairs: z0g+0..3

    // ---- flow loads (scalar, lane-coalesced) issued while DMAs fly ----
    float fzk[4], fyk[4], fxk[4];
    int sk[4];
#pragma unroll
    for (int it = 0; it < 4; ++it) {
        sk[it] = (((z0g + it) * H_ + y) << 7) + x;
        fzk[it] = fb[sk[it]];
        fyk[it] = fb[S_ + sk[it]];
        fxk[it] = fb[2 * S_ + sk[it]];
    }

    __syncthreads();   // single vmcnt(0) drain covers DMAs + flow

    const int zlo = max(0, zb - RZ), zhi = min(D_, zb + ZT + RZ);
    const int ylo = max(0, yb - RY), yhi = min(H_, yb + YT + RY);
    const int xlo = max(0, xb - RX), xhi = min(W_, xb + XT + RX);

    // ---- compute + store: 4 pairs, scalar coalesced stores ----
#pragma unroll
    for (int it = 0; it < 4; ++it) {
        const float2 v = compute_pair(x, y, z0g + it, fzk[it], fyk[it], fxk[it],
                                      zb, yb, xb, zlo, zhi, ylo, yhi,
                                      xlo, xhi, tile, s0);
        o0[sk[it]]      = v.x;
        o0[S_ + sk[it]] = v.y;
    }
}

extern "C" void kernel_launch(void* const* d_in, const int* in_sizes, int n_in,
                              void* d_out, int out_size, void* d_ws, size_t ws_size,
                              hipStream_t stream) {
    const float* src  = (const float*)d_in[0];
    const float* flow = (const float*)d_in[1];
    float* out = (float*)d_out;

    // grid: x 4, y 20, z = 16 z-tiles x B2 = 32 -> 2560 blocks
    //     = 5 exact residency rounds at 2 blocks/CU.
    dim3 grid(W_ / XT, H_ / YT, (D_ / ZT) * B_);
    warp3d_tile<<<grid, NTHREADS, 0, stream>>>(src, flow, out);
}